// Round 6
// baseline (369.729 us; speedup 1.0000x reference)
//
#include <hip/hip_runtime.h>
#include <stdint.h>

// KMaxPool: rows of S=4096 f32, top-K=8 values, output in original index order.
// One wave per row, NON-persistent.
//
// R6: high-occupancy register-chunked design. Post-mortem R1-R5: every ~60us
// kernel had <=8-16 waves/CU and a full-row-resident + vmcnt(0)-drain
// structure; the harness fill kernel (max occupancy, trivial) hits 6.7 TB/s.
// New structure: threshold T1 from chunk 0 only (exact 8th of its 512 pairwise
// submaxes, provably <= row 8th-largest), rescan chunk 0 from live registers,
// then stream chunks 1-3 comparing vs T1. No LDS row, no full-row residency,
// peak ~50 VGPR -> launch_bounds(256,6): 24 waves/CU (3x R3). LDS = keys only.
#define WPB  4
#define CAP  192
#define KK   8
#define SLEN 4096

__global__ __launch_bounds__(256, 6)
void kmax_kernel(const float* __restrict__ x, float* __restrict__ out, int nrows) {
    const int wave = threadIdx.x >> 6;
    const int lane = threadIdx.x & 63;
    const int row  = blockIdx.x * WPB + wave;

    __shared__ int                s_cnt[WPB];
    __shared__ unsigned long long s_key[WPB][CAP];   // 6 KiB

    if (row >= nrows) return;        // no barriers anywhere -> safe
    if (lane == 0) s_cnt[wave] = 0;

    const float4* xr = reinterpret_cast<const float4*>(x + (size_t)row * SLEN);

    // ---- chunk 0 (elements 0..1023): 4 float4/lane, kept in registers
    float4 c0[4];
    #pragma unroll
    for (int j = 0; j < 4; ++j) c0[j] = xr[j * 64 + lane];

    // 8 pairwise submaxes/lane (512 submaxes over chunk 0)
    float m[8];
    m[0] = fmaxf(c0[0].x, c0[2].x);  m[1] = fmaxf(c0[0].y, c0[2].y);
    m[2] = fmaxf(c0[0].z, c0[2].z);  m[3] = fmaxf(c0[0].w, c0[2].w);
    m[4] = fmaxf(c0[1].x, c0[3].x);  m[5] = fmaxf(c0[1].y, c0[3].y);
    m[6] = fmaxf(c0[1].z, c0[3].z);  m[7] = fmaxf(c0[1].w, c0[3].w);

    // sort m[0..7] descending (Batcher, 19 CAS)
    #define MCAS(a, b) { float hi = fmaxf(m[a], m[b]); float lo = fminf(m[a], m[b]); m[a] = hi; m[b] = lo; }
    MCAS(0,1) MCAS(2,3) MCAS(4,5) MCAS(6,7)
    MCAS(0,2) MCAS(1,3) MCAS(4,6) MCAS(5,7)
    MCAS(1,2) MCAS(5,6)
    MCAS(0,4) MCAS(1,5) MCAS(2,6) MCAS(3,7)
    MCAS(2,4) MCAS(3,5)
    MCAS(1,2) MCAS(3,4) MCAS(5,6)
    #undef MCAS

    // butterfly top-8 merge across 64 lanes -> exact sorted top-8 of the 512
    // chunk-0 submaxes in every lane
    #pragma unroll
    for (int s = 1; s < 64; s <<= 1) {
        float b[8], t[8];
        #pragma unroll
        for (int i = 0; i < 8; ++i) b[i] = __shfl_xor(m[i], s, 64);
        #pragma unroll
        for (int i = 0; i < 8; ++i) t[i] = fmaxf(m[i], b[7 - i]);
        #define BCAS(a, c) { float hi = fmaxf(t[a], t[c]); float lo = fminf(t[a], t[c]); t[a] = hi; t[c] = lo; }
        BCAS(0,4) BCAS(1,5) BCAS(2,6) BCAS(3,7)
        BCAS(0,2) BCAS(1,3) BCAS(4,6) BCAS(5,7)
        BCAS(0,1) BCAS(2,3) BCAS(4,5) BCAS(6,7)
        #undef BCAS
        #pragma unroll
        for (int i = 0; i < 8; ++i) m[i] = t[i];
    }
    // T1 = 8th-largest submax of chunk 0 <= chunk-0 8th-largest <= row
    // 8th-largest  =>  valid global threshold; >=8 chunk-0 elements >= T1.
    const float T1 = m[7];

    // key = (orderedfloat(val)<<32) | (4095 - idx); key desc == (val desc, idx asc)
    #define PUSH(val, idx) { \
        int p = atomicAdd(&s_cnt[wave], 1); \
        if (p < CAP) { \
            unsigned u = __float_as_uint(val); \
            u ^= ((unsigned)((int)u >> 31)) | 0x80000000u; \
            s_key[wave][p] = ((unsigned long long)u << 32) | (unsigned)(4095 - (idx)); \
        } }

    // ---- rescan chunk 0 from live registers
    #pragma unroll
    for (int j = 0; j < 4; ++j) {
        const float4 v = c0[j];
        const int base = (j * 64 + lane) * 4;
        if (v.x >= T1) PUSH(v.x, base + 0)
        if (v.y >= T1) PUSH(v.y, base + 1)
        if (v.z >= T1) PUSH(v.z, base + 2)
        if (v.w >= T1) PUSH(v.w, base + 3)
    }

    // ---- stream chunks 1..3, compare vs T1, registers die immediately
    #pragma unroll
    for (int c = 1; c < 4; ++c) {
        float4 v[4];
        #pragma unroll
        for (int j = 0; j < 4; ++j) v[j] = xr[c * 256 + j * 64 + lane];
        #pragma unroll
        for (int j = 0; j < 4; ++j) {
            const int base = (c * 256 + j * 64 + lane) * 4;
            if (v[j].x >= T1) PUSH(v[j].x, base + 0)
            if (v[j].y >= T1) PUSH(v[j].y, base + 1)
            if (v[j].z >= T1) PUSH(v[j].z, base + 2)
            if (v[j].w >= T1) PUSH(v[j].w, base + 3)
        }
    }
    #undef PUSH

    asm volatile("s_waitcnt lgkmcnt(0)" ::: "memory");  // wave-private DS in order

    int n = s_cnt[wave];
    if (n > CAP) n = CAP;

    // ---- all lanes redundantly insertion-select top-8 keys (broadcast LDS
    // reads -> wave-uniform branch, taken only when a key enters the top-8)
    unsigned long long kk[KK];
    #pragma unroll
    for (int i = 0; i < KK; ++i) kk[i] = 0ull;
    for (int i = 0; i < n; ++i) {
        unsigned long long c = s_key[wave][i];
        if (c > kk[7]) {
            #pragma unroll
            for (int t = 7; t > 0; --t)
                kk[t] = (c > kk[t - 1]) ? kk[t - 1] : ((c > kk[t]) ? c : kk[t]);
            kk[0] = (c > kk[0]) ? c : kk[0];
        }
    }

    // ---- reorder winners by ascending original index == descending low32
    #define ICAS(a, b) { bool sw = (unsigned)kk[a] < (unsigned)kk[b]; \
        unsigned long long hi = sw ? kk[b] : kk[a]; \
        unsigned long long lo = sw ? kk[a] : kk[b]; \
        kk[a] = hi; kk[b] = lo; }
    ICAS(0,1) ICAS(2,3) ICAS(4,5) ICAS(6,7)
    ICAS(0,2) ICAS(1,3) ICAS(4,6) ICAS(5,7)
    ICAS(1,2) ICAS(5,6)
    ICAS(0,4) ICAS(1,5) ICAS(2,6) ICAS(3,7)
    ICAS(2,4) ICAS(3,5)
    ICAS(1,2) ICAS(3,4) ICAS(5,6)
    #undef ICAS

    if (lane == 0) {
        float vals[KK];
        #pragma unroll
        for (int i = 0; i < KK; ++i) {
            unsigned g = (unsigned)(kk[i] >> 32);
            unsigned msk = ((int)g < 0) ? 0x80000000u : 0xFFFFFFFFu;
            vals[i] = __uint_as_float(g ^ msk);
        }
        float4* o = reinterpret_cast<float4*>(out + (size_t)row * KK);
        o[0] = make_float4(vals[0], vals[1], vals[2], vals[3]);
        o[1] = make_float4(vals[4], vals[5], vals[6], vals[7]);
    }
}

extern "C" void kernel_launch(void* const* d_in, const int* in_sizes, int n_in,
                              void* d_out, int out_size, void* d_ws, size_t ws_size,
                              hipStream_t stream) {
    const float* x = (const float*)d_in[0];
    float* out = (float*)d_out;
    const int nrows = out_size / KK;                 // 16 * 1024 = 16384
    const int blocks = (nrows + WPB - 1) / WPB;      // 4096
    kmax_kernel<<<blocks, 256, 0, stream>>>(x, out, nrows);
}